// Round 2
// baseline (156.133 us; speedup 1.0000x reference)
//
#include <hip/hip_runtime.h>
#include <math.h>

// Problem constants (from reference)
#define TT 10
#define SS 10
#define RR 2000
#define KK 100
#define OO 500
#define PP (TT*SS*RR)        // 200000 particles
#define NUNITS 6250          // 32-row units (2 MFMA M-tiles each)
#define NT 7                 // 7 N-tiles of 16 cols -> 112 padded assemblages
#define WAVES 12             // waves per block
#define BLOCKT (WAVES*64)    // 768 threads
#define NWAVES_TOTAL (256*WAVES)
#define EPSF 1e-6f

typedef float        f32x4  __attribute__((ext_vector_type(4)));
typedef unsigned int u32x4  __attribute__((ext_vector_type(4)));
typedef __bf16       bf16x8 __attribute__((ext_vector_type(8)));

union BFU { bf16x8 v; u32x4 q; };

// XOR swizzle: spreads the 16B chunks of a row across bank-quads so that
// B-frag ds_read_b128 (16 lanes read rows nt*16+lo at the same k-offset,
// i.e. stride 1024B) avoids the worst-case same-bank serialization.
__device__ __forceinline__ int swz(int row, int byteInRow) {
    return row * 1024 + (byteInRow ^ ((row & 7) << 4));
}

// ---------------------------------------------------------------------------
// Prep: theta = softmax(theta_params) -> out[1..50001); beta copy -> out[50001..);
// out[0] = 0 (accumulator for -loglik).
// ---------------------------------------------------------------------------
__global__ __launch_bounds__(64) void mcspace_prep(
    const float* __restrict__ theta_params,
    const float* __restrict__ beta,
    float* __restrict__ out)
{
    const int b  = blockIdx.x;
    const int ln = threadIdx.x;   // 64 lanes, one wave
    if (b < KK) {
        const float* tp = theta_params + b * OO;
        float x[8];
        #pragma unroll
        for (int j = 0; j < 8; ++j) {
            int o = ln + 64 * j;
            x[j] = (o < OO) ? tp[o] : -INFINITY;
        }
        float mx = x[0];
        #pragma unroll
        for (int j = 1; j < 8; ++j) mx = fmaxf(mx, x[j]);
        #pragma unroll
        for (int w = 1; w < 64; w <<= 1) mx = fmaxf(mx, __shfl_xor(mx, w));
        float e[8], sm = 0.f;
        #pragma unroll
        for (int j = 0; j < 8; ++j) { e[j] = __expf(x[j] - mx); sm += e[j]; }
        #pragma unroll
        for (int w = 1; w < 64; w <<= 1) sm += __shfl_xor(sm, w);
        const float inv = 1.f / sm;
        float* to = out + 1 + b * OO;
        #pragma unroll
        for (int j = 0; j < 8; ++j) {
            int o = ln + 64 * j;
            if (o < OO) to[o] = e[j] * inv;
        }
    } else {
        int idx = (b - KK) * 64 + ln;
        if (idx < KK * TT * SS) out[1 + KK * OO + idx] = beta[idx];
        if (b == KK && ln == 0) out[0] = 0.f;
    }
}

// ---------------------------------------------------------------------------
// Main: rlog = counts @ logtheta^T via bf16 MFMA (2 M-tiles per wave unit),
// then beta-weighted logsumexp over assemblages, accumulate -sum into out[0].
// ---------------------------------------------------------------------------
__global__ __launch_bounds__(BLOCKT) void mcspace_main(
    const float* __restrict__ counts,
    const float* __restrict__ theta_params,
    const float* __restrict__ beta,
    float* __restrict__ out)
{
    __shared__ u32x4 ldsB[7168];   // logtheta bf16 [112][512], swizzled rows (112 KB)
    __shared__ float red[WAVES];
    char* ldsBytes = (char*)&ldsB[0];

    const int tid = threadIdx.x;
    const int wv  = tid >> 6;     // wave id 0..11
    const int ln  = tid & 63;
    const int lo  = ln & 15;
    const int g   = ln >> 4;

    // ---- build logtheta bf16 [112][512] in LDS (rows strided by WAVES) ----
    for (int it = 0; it < 10; ++it) {
        const int row = wv + WAVES * it;       // 0..119
        if (row >= 112) break;
        BFU w8; w8.q = (u32x4){0u, 0u, 0u, 0u};
        if (row < KK) {
            const float* tp = theta_params + row * OO;
            float x[8];
            #pragma unroll
            for (int j = 0; j < 8; ++j) {
                int o = ln * 8 + j;
                x[j] = (o < OO) ? tp[o] : -INFINITY;
            }
            float mx = x[0];
            #pragma unroll
            for (int j = 1; j < 8; ++j) mx = fmaxf(mx, x[j]);
            #pragma unroll
            for (int w = 1; w < 64; w <<= 1) mx = fmaxf(mx, __shfl_xor(mx, w));
            float e[8], sm = 0.f;
            #pragma unroll
            for (int j = 0; j < 8; ++j) { e[j] = __expf(x[j] - mx); sm += e[j]; }
            #pragma unroll
            for (int w = 1; w < 64; w <<= 1) sm += __shfl_xor(sm, w);
            const float inv = 1.f / sm;
            #pragma unroll
            for (int j = 0; j < 8; ++j)
                w8.v[j] = (__bf16)__logf(e[j] * inv + EPSF);  // log(theta + EPS)
        }
        *(u32x4*)(ldsBytes + swz(row, ln * 16)) = w8.q;
    }
    __syncthreads();

    float wacc = 0.f;
    const int gw = blockIdx.x * WAVES + wv;   // global wave id
    const int kb = g * 8;                     // k base within 32-step for this lane group

    for (int unit = gw; unit < NUNITS; unit += NWAVES_TOTAL) {
        const int pbase = unit * 32;
        const int ts = pbase / RR;            // same (t,s) for all 32 rows (2000%32==0)
        const float* rp0 = counts + (long)(pbase + lo) * OO;
        const float* rp1 = rp0 + 16 * OO;

        f32x4 acc0[NT], acc1[NT];
        #pragma unroll
        for (int nt = 0; nt < NT; ++nt) {
            acc0[nt] = (f32x4){0.f, 0.f, 0.f, 0.f};
            acc1[nt] = (f32x4){0.f, 0.f, 0.f, 0.f};
        }

        // 15 full K-steps of 32 (k = 0..479)
        #pragma unroll 3
        for (int ko = 0; ko < 15; ++ko) {
            f32x4 a0 = *(const f32x4*)(rp0 + ko * 32 + kb);
            f32x4 a1 = *(const f32x4*)(rp0 + ko * 32 + kb + 4);
            f32x4 b0 = *(const f32x4*)(rp1 + ko * 32 + kb);
            f32x4 b1 = *(const f32x4*)(rp1 + ko * 32 + kb + 4);
            BFU aA, aB;
            #pragma unroll
            for (int j = 0; j < 4; ++j) {
                aA.v[j]     = (__bf16)a0[j];
                aA.v[4 + j] = (__bf16)a1[j];
                aB.v[j]     = (__bf16)b0[j];
                aB.v[4 + j] = (__bf16)b1[j];
            }
            const int bb = ko * 64 + g * 16;
            #pragma unroll
            for (int nt = 0; nt < NT; ++nt) {
                BFU bv;
                bv.q = *(const u32x4*)(ldsBytes + swz(nt * 16 + lo, bb));
                acc0[nt] = __builtin_amdgcn_mfma_f32_16x16x32_bf16(aA.v, bv.v, acc0[nt], 0, 0, 0);
                acc1[nt] = __builtin_amdgcn_mfma_f32_16x16x32_bf16(aB.v, bv.v, acc1[nt], 0, 0, 0);
            }
        }
        // remainder K-step: k = 480..511, only k < 500 valid (guard avoids OOB)
        {
            BFU aA, aB;
            #pragma unroll
            for (int j = 0; j < 8; ++j) {
                int k = 480 + kb + j;
                aA.v[j] = (__bf16)((k < OO) ? rp0[k] : 0.f);
                aB.v[j] = (__bf16)((k < OO) ? rp1[k] : 0.f);
            }
            const int bb = 15 * 64 + g * 16;
            #pragma unroll
            for (int nt = 0; nt < NT; ++nt) {
                BFU bv;
                bv.q = *(const u32x4*)(ldsBytes + swz(nt * 16 + lo, bb));
                acc0[nt] = __builtin_amdgcn_mfma_f32_16x16x32_bf16(aA.v, bv.v, acc0[nt], 0, 0, 0);
                acc1[nt] = __builtin_amdgcn_mfma_f32_16x16x32_bf16(aB.v, bv.v, acc1[nt], 0, 0, 0);
            }
        }

        // beta for this unit's (t,s): lane lo owns column j = nt*16+lo
        float bet[NT];
        #pragma unroll
        for (int nt = 0; nt < NT; ++nt) {
            int j = nt * 16 + lo;
            bet[nt] = (j < KK) ? beta[j * (TT * SS) + ts] : 0.f;
        }

        // ---- beta-weighted logsumexp over assemblages, both tiles ----
        // D layout: lane holds rows i = 4*g + r (r=0..3) at column j = nt*16+lo.
        float mA[4] = {-INFINITY, -INFINITY, -INFINITY, -INFINITY};
        float mB[4] = {-INFINITY, -INFINITY, -INFINITY, -INFINITY};
        #pragma unroll
        for (int nt = 0; nt < NT; ++nt) {
            const bool valid = (nt * 16 + lo) < KK;
            #pragma unroll
            for (int r = 0; r < 4; ++r) {
                mA[r] = fmaxf(mA[r], valid ? acc0[nt][r] : -INFINITY);
                mB[r] = fmaxf(mB[r], valid ? acc1[nt][r] : -INFINITY);
            }
        }
        #pragma unroll
        for (int w = 1; w < 16; w <<= 1) {
            #pragma unroll
            for (int r = 0; r < 4; ++r) {
                mA[r] = fmaxf(mA[r], __shfl_xor(mA[r], w));
                mB[r] = fmaxf(mB[r], __shfl_xor(mB[r], w));
            }
        }
        float sA[4] = {0.f, 0.f, 0.f, 0.f};
        float sB[4] = {0.f, 0.f, 0.f, 0.f};
        #pragma unroll
        for (int nt = 0; nt < NT; ++nt) {
            const bool valid = (nt * 16 + lo) < KK;
            #pragma unroll
            for (int r = 0; r < 4; ++r) {
                sA[r] += bet[nt] * __expf(valid ? (acc0[nt][r] - mA[r]) : -INFINITY);
                sB[r] += bet[nt] * __expf(valid ? (acc1[nt][r] - mB[r]) : -INFINITY);
            }
        }
        #pragma unroll
        for (int w = 1; w < 16; w <<= 1) {
            #pragma unroll
            for (int r = 0; r < 4; ++r) {
                sA[r] += __shfl_xor(sA[r], w);
                sB[r] += __shfl_xor(sB[r], w);
            }
        }
        if (lo == 0) {
            #pragma unroll
            for (int r = 0; r < 4; ++r)
                wacc += (mA[r] + __logf(sA[r] + EPSF)) + (mB[r] + __logf(sB[r] + EPSF));
        }
    }

    // block reduction (deterministic), then one atomic per block
    #pragma unroll
    for (int w = 1; w < 64; w <<= 1) wacc += __shfl_xor(wacc, w);
    if (ln == 0) red[wv] = wacc;
    __syncthreads();
    if (tid == 0) {
        float s = 0.f;
        #pragma unroll
        for (int i = 0; i < WAVES; ++i) s += red[i];
        atomicAdd(out, -s);   // elbo_loss = -loglik
    }
}

extern "C" void kernel_launch(void* const* d_in, const int* in_sizes, int n_in,
                              void* d_out, int out_size, void* d_ws, size_t ws_size,
                              hipStream_t stream)
{
    (void)in_sizes; (void)n_in; (void)d_ws; (void)ws_size; (void)out_size;
    const float* counts       = (const float*)d_in[0];
    const float* theta_params = (const float*)d_in[1];
    const float* beta         = (const float*)d_in[2];
    float* out = (float*)d_out;

    // prep: 100 softmax rows + 157 beta-copy blocks (one wave each)
    mcspace_prep<<<dim3(KK + (KK * TT * SS + 63) / 64), dim3(64), 0, stream>>>(
        theta_params, beta, out);
    // main: 256 blocks (1/CU) x 12 waves, wave-strided over 6250 32-row units
    mcspace_main<<<dim3(256), dim3(BLOCKT), 0, stream>>>(
        counts, theta_params, beta, out);
}

// Round 3
// 144.832 us; speedup vs baseline: 1.0780x; 1.0780x over previous
//
#include <hip/hip_runtime.h>
#include <math.h>

// Problem constants (from reference)
#define TT 10
#define SS 10
#define RR 2000
#define KK 100
#define OO 500
#define PP (TT*SS*RR)          // 200000 particles
#define TROWS 32               // rows per block-tile
#define NTILES (PP/TROWS)      // 6250
#define NBLK 256
#define WAVES 14               // 2 M-tiles x 7 N-tiles
#define BLOCKT (WAVES*64)      // 896 threads
#define CHUNKS 4000            // 16B f32 chunks per tile (32 rows * 2000B / 16)
#define CPT 5                  // max chunks per thread
#define RLP 114                // rlog row pitch (f32) — 114%32=18, g-groups spread
#define EPSF 1e-6f

typedef float        f32x4  __attribute__((ext_vector_type(4)));
typedef unsigned int u32x4  __attribute__((ext_vector_type(4)));
typedef unsigned int u32x2  __attribute__((ext_vector_type(2)));
typedef __bf16       bf16x8 __attribute__((ext_vector_type(8)));
typedef __bf16       bf16x4 __attribute__((ext_vector_type(4)));

union BFU { bf16x8 v; u32x4 q; };
union BF4 { bf16x4 v; u32x2 q; };

// XOR swizzle within a 1024B row: spreads 16B granules across bank groups so
// stride-1024B column reads (ds_read_b128, 16 lanes) are conflict-free.
__device__ __forceinline__ int swz(int row, int byteInRow) {
    return row * 1024 + (byteInRow ^ ((row & 7) << 4));
}

// ---------------------------------------------------------------------------
// Prep: theta = softmax(theta_params) -> out[1..50001); beta copy -> out[50001..);
// out[0] = 0 (accumulator for -loglik).
// ---------------------------------------------------------------------------
__global__ __launch_bounds__(64) void mcspace_prep(
    const float* __restrict__ theta_params,
    const float* __restrict__ beta,
    float* __restrict__ out)
{
    const int b  = blockIdx.x;
    const int ln = threadIdx.x;
    if (b < KK) {
        const float* tp = theta_params + b * OO;
        float x[8];
        #pragma unroll
        for (int j = 0; j < 8; ++j) {
            int o = ln + 64 * j;
            x[j] = (o < OO) ? tp[o] : -INFINITY;
        }
        float mx = x[0];
        #pragma unroll
        for (int j = 1; j < 8; ++j) mx = fmaxf(mx, x[j]);
        #pragma unroll
        for (int w = 1; w < 64; w <<= 1) mx = fmaxf(mx, __shfl_xor(mx, w));
        float e[8], sm = 0.f;
        #pragma unroll
        for (int j = 0; j < 8; ++j) { e[j] = __expf(x[j] - mx); sm += e[j]; }
        #pragma unroll
        for (int w = 1; w < 64; w <<= 1) sm += __shfl_xor(sm, w);
        const float inv = 1.f / sm;
        float* to = out + 1 + b * OO;
        #pragma unroll
        for (int j = 0; j < 8; ++j) {
            int o = ln + 64 * j;
            if (o < OO) to[o] = e[j] * inv;
        }
    } else {
        int idx = (b - KK) * 64 + ln;
        if (idx < KK * TT * SS) out[1 + KK * OO + idx] = beta[idx];
        if (b == KK && ln == 0) out[0] = 0.f;
    }
}

// ---------------------------------------------------------------------------
// Main: block-cooperative. Per 32-row tile: sequential-coalesced f32 load ->
// regs -> bf16 -> swizzled LDS A; MFMA vs LDS-resident logtheta (B);
// rlog transpose in LDS; per-row beta-weighted logsumexp; atomicAdd.
// ---------------------------------------------------------------------------
__global__ __launch_bounds__(BLOCKT) void mcspace_main(
    const float* __restrict__ counts,
    const float* __restrict__ theta_params,
    const float* __restrict__ beta,
    float* __restrict__ out)
{
    __shared__ u32x4 ldsB[112 * 64];   // logtheta bf16 [112][512], swizzled (112 KB)
    __shared__ u32x4 ldsA[32 * 64];    // counts bf16 [32][512], swizzled (32 KB)
    __shared__ float rlog[32 * RLP];   // [32][114] f32 (14.25 KB)
    __shared__ float betaT[2 * 112];   // beta columns for the tile's 1-2 ts values
    __shared__ float red[WAVES];
    char* bB = (char*)ldsB;
    char* bA = (char*)ldsA;

    const int tid = threadIdx.x;
    const int wv  = tid >> 6;
    const int ln  = tid & 63;
    const int lo  = ln & 15;
    const int g   = ln >> 4;
    const int b   = blockIdx.x;

    const int ntile_mine = (NTILES - b + NBLK - 1) / NBLK;  // tiles b, b+256, ...

    // ---- issue tile-0 loads first (hide under B build) ----
    f32x4 cur[CPT];
    {
        long tf = (long)b * (TROWS * OO);
        #pragma unroll
        for (int j = 0; j < CPT; ++j) {
            int c = tid + j * BLOCKT;
            if (c < CHUNKS) cur[j] = *(const f32x4*)(counts + tf + (long)c * 4);
        }
    }

    // ---- build logtheta bf16 [112][512] in LDS (rows wv + 14*it) ----
    for (int it = 0; it < 8; ++it) {
        const int row = wv + WAVES * it;       // 0..111, bijective
        BFU w8; w8.q = (u32x4){0u, 0u, 0u, 0u};
        if (row < KK) {
            const float* tp = theta_params + row * OO;
            float x[8];
            #pragma unroll
            for (int j = 0; j < 8; ++j) {
                int o = ln * 8 + j;
                x[j] = (o < OO) ? tp[o] : -INFINITY;
            }
            float mx = x[0];
            #pragma unroll
            for (int j = 1; j < 8; ++j) mx = fmaxf(mx, x[j]);
            #pragma unroll
            for (int w = 1; w < 64; w <<= 1) mx = fmaxf(mx, __shfl_xor(mx, w));
            float e[8], sm = 0.f;
            #pragma unroll
            for (int j = 0; j < 8; ++j) { e[j] = __expf(x[j] - mx); sm += e[j]; }
            #pragma unroll
            for (int w = 1; w < 64; w <<= 1) sm += __shfl_xor(sm, w);
            const float inv = 1.f / sm;
            #pragma unroll
            for (int j = 0; j < 8; ++j)
                w8.v[j] = (__bf16)__logf(e[j] * inv + EPSF);  // log(theta+EPS)
        }
        *(u32x4*)(bB + swz(row, ln * 16)) = w8.q;
    }

    // ---- zero A's k-padding (pre-swizzle bytes [1000,1024) of each row) ----
    if (tid < 32) {
        const int row = tid;
        u32x2 z = (u32x2){0u, 0u};
        *(u32x2*)(bA + swz(row, 1000)) = z;
        *(u32x2*)(bA + swz(row, 1008)) = z;
        *(u32x2*)(bA + swz(row, 1016)) = z;
    }

    const int m  = wv / 7;                 // 0..1  (M-tile)
    const int nt = wv % 7;                 // 0..6  (N-tile)
    const int xr = (lo & 7) << 4;
    const int baseAoff = (m * 16 + lo) * 1024;
    const int baseBoff = (nt * 16 + lo) * 1024;
    const int g16 = g * 16;

    float wacc = 0.f;

    for (int it = 0; it < ntile_mine; ++it) {
        const int tile   = b + it * NBLK;
        const int pbase  = tile * TROWS;
        const int ts0    = pbase / (RR);             // RR=2000
        const int rb     = (ts0 + 1) * RR - pbase;   // rows >= rb belong to ts0+1
        const int ts1    = ts0 + ((rb < TROWS) ? 1 : 0);

        __syncthreads();   // S1: A + rlog free (prev k-loop & row-pass done)

        // ---- cvt + swizzled ds_write of tile's A ----
        #pragma unroll
        for (int j = 0; j < CPT; ++j) {
            int c = tid + j * BLOCKT;
            if (c < CHUNKS) {
                int row = c / 125;        // 125 chunks (2000B) per row
                int kc  = c % 125;
                BF4 w;
                #pragma unroll
                for (int q = 0; q < 4; ++q) w.v[q] = (__bf16)cur[j][q];
                *(u32x2*)(bA + swz(row, kc * 8)) = w.q;
            }
        }

        // ---- prefetch next tile into regs (covered by compute below) ----
        if (it + 1 < ntile_mine) {
            long tf = (long)(tile + NBLK) * (TROWS * OO);
            #pragma unroll
            for (int j = 0; j < CPT; ++j) {
                int c = tid + j * BLOCKT;
                if (c < CHUNKS) cur[j] = *(const f32x4*)(counts + tf + (long)c * 4);
            }
        }

        __syncthreads();   // S2: A visible

        // ---- K-loop: 16 steps of 32, one MFMA per step ----
        f32x4 acc = (f32x4){0.f, 0.f, 0.f, 0.f};
        #pragma unroll
        for (int ko = 0; ko < 16; ++ko) {
            const int t = (ko * 64 + g16) ^ xr;
            BFU av, bv;
            av.q = *(const u32x4*)(bA + baseAoff + t);
            bv.q = *(const u32x4*)(bB + baseBoff + t);
            acc = __builtin_amdgcn_mfma_f32_16x16x32_bf16(av.v, bv.v, acc, 0, 0, 0);
        }

        // ---- acc -> rlog transpose (D: row = m*16+4g+r, col = nt*16+lo) ----
        #pragma unroll
        for (int r = 0; r < 4; ++r)
            rlog[(m * 16 + 4 * g + r) * RLP + nt * 16 + lo] = acc[r];

        // ---- stage beta columns for ts0 / ts1 ----
        if (tid < 112) {
            betaT[tid] = (tid < KK) ? beta[tid * (TT * SS) + ts0] : 0.f;
        } else if (tid < 224) {
            int j = tid - 112;
            betaT[112 + j] = (j < KK) ? beta[j * (TT * SS) + ts1] : 0.f;
        }

        __syncthreads();   // S3: rlog + betaT ready (k-loop done for all)

        // ---- per-row beta-weighted logsumexp (rows wv, wv+14, wv+28) ----
        for (int row = wv; row < TROWS; row += WAVES) {
            const int sel = (row >= rb) ? 112 : 0;
            const float v1 = rlog[row * RLP + ln];               // col = ln (<100)
            const float b1 = betaT[sel + ln];
            const bool  ok2 = (ln < 36);                         // col2 = 64+ln < 100
            const float v2 = ok2 ? rlog[row * RLP + 64 + ln] : -INFINITY;
            const float b2 = ok2 ? betaT[sel + 64 + ln] : 0.f;
            float mx = fmaxf(v1, v2);
            #pragma unroll
            for (int w = 1; w < 64; w <<= 1) mx = fmaxf(mx, __shfl_xor(mx, w));
            float s = b1 * __expf(v1 - mx) + b2 * __expf(v2 - mx);
            #pragma unroll
            for (int w = 1; w < 64; w <<= 1) s += __shfl_xor(s, w);
            if (ln == 0) wacc += mx + __logf(s + EPSF);
        }
    }

    // ---- deterministic block reduction, one atomic per block ----
    #pragma unroll
    for (int w = 1; w < 64; w <<= 1) wacc += __shfl_xor(wacc, w);
    if (ln == 0) red[wv] = wacc;
    __syncthreads();
    if (tid == 0) {
        float s = 0.f;
        #pragma unroll
        for (int i = 0; i < WAVES; ++i) s += red[i];
        atomicAdd(out, -s);   // elbo_loss = -loglik
    }
}

extern "C" void kernel_launch(void* const* d_in, const int* in_sizes, int n_in,
                              void* d_out, int out_size, void* d_ws, size_t ws_size,
                              hipStream_t stream)
{
    (void)in_sizes; (void)n_in; (void)d_ws; (void)ws_size; (void)out_size;
    const float* counts       = (const float*)d_in[0];
    const float* theta_params = (const float*)d_in[1];
    const float* beta         = (const float*)d_in[2];
    float* out = (float*)d_out;

    mcspace_prep<<<dim3(KK + (KK * TT * SS + 63) / 64), dim3(64), 0, stream>>>(
        theta_params, beta, out);
    mcspace_main<<<dim3(NBLK), dim3(BLOCKT), 0, stream>>>(
        counts, theta_params, beta, out);
}